// Round 1
// 2854.192 us; speedup vs baseline: 1.1265x; 1.1265x over previous
//
#include <hip/hip_runtime.h>
#include <math.h>

#define BATCH 4096
#define LDIM 1024
#define HDIM 2048
#define ODIM 512
#define GDIM 3072   // 3*LDIM
#define JDIM 1536   // IDIM+ODIM == LDIM+ODIM
#define INNER 4
#define OUTER 8

using f16 = _Float16;
using f16x4 = __attribute__((ext_vector_type(4))) _Float16;
using f16x8 = __attribute__((ext_vector_type(8))) _Float16;
using f32x4 = __attribute__((ext_vector_type(4))) float;

typedef __attribute__((address_space(3))) void lds_void;
typedef __attribute__((address_space(1))) void glob_void;

__device__ __forceinline__ void gload16(const void* g, void* l) {
  __builtin_amdgcn_global_load_lds((const glob_void*)g, (lds_void*)l, 16, 0, 0);
}

#define MFMA16(a, b, c) __builtin_amdgcn_mfma_f32_16x16x32_f16(a, b, c, 0, 0, 0)

__device__ __forceinline__ float fast_sigmoid(float x) {
  return __builtin_amdgcn_rcpf(1.0f + __expf(-x));
}
__device__ __forceinline__ float fast_tanh(float x) {
  // tanh(x) = 1 - 2/(1+e^{2x}); saturates correctly at +/-inf of the exp
  return 1.0f - 2.0f * __builtin_amdgcn_rcpf(1.0f + __expf(2.0f * x));
}

// fp32 -> fp16 (RTN), n4 = elems/4
__global__ __launch_bounds__(256) void convert_w(const float* __restrict__ src,
                                                 f16* __restrict__ dst, int n4) {
  int i = blockIdx.x * 256 + threadIdx.x;
  if (i >= n4) return;
  float4 v = ((const float4*)src)[i];
  f16x4 d = {(f16)v.x, (f16)v.y, (f16)v.z, (f16)v.w};
  *(f16x4*)&dst[(size_t)i * 4] = d;
}

// inputs [B,1024] fp32 -> cols [0,1024) of catX [B,1536] fp16
__global__ __launch_bounds__(256) void input_to_cat(
    const float* __restrict__ inp, f16* __restrict__ cH) {
  int idx = blockIdx.x * 256 + threadIdx.x;  // over B*256 float4s
  if (idx >= BATCH * 256) return;
  int row = idx >> 8, c4 = idx & 255;
  float4 v = ((const float4*)inp)[idx];
  f16x4 h4 = {(f16)v.x, (f16)v.y, (f16)v.z, (f16)v.w};
  *(f16x4*)&cH[(size_t)row * JDIM + c4 * 4] = h4;
}

// ============================================================================
// fp16 GEMM: C[4096, N] = epi(A @ W^T + bias). A fp16 [M][K], W fp16 [N][K].
// Tile 128x128, BK=32, 4 waves (2x2), wave 64x64 = 4x4 frags, 1 MFMA/frag.
// Double-buffered LDS with prefetch: STAGE(b^1,k+32) issued BEFORE compute(b),
// single barrier per K-step -> load latency hidden under ds_read+MFMA.
// EPI: 0 = PACKED fp16 C (xg layout [m/4][N][4], f16x4 along m — matches the
//          MFMA C-frag (4 consecutive rows/lane) so store is one 8B op and
//          the GRU consumer loads are vectorized+coalesced)
//      1 = combined joint head: relu; n<2048 -> h1 fp16 [m][2048] (bias),
//          n>=2048 -> h2 fp32 [m][1024] (bias2)
//      2 = logits: fp32 Cout (N=512) + tanh -> fp16 into catX/catJ ans cols
// ============================================================================
template <int EPI>
__global__ __launch_bounds__(256, 2) void gemm_f16(
    const f16* __restrict__ A, const f16* __restrict__ W,
    const float* __restrict__ bias, const float* __restrict__ bias2,
    f16* __restrict__ Ch, float* __restrict__ Cf, float* __restrict__ Cout,
    f16* __restrict__ aXH, f16* __restrict__ aJH, int N, int K) {
  __shared__ f16 sA[2][128 * 32];
  __shared__ f16 sW[2][128 * 32];
  const int tid = threadIdx.x;
  const int w = tid >> 6, lane = tid & 63;
  const int wm = w >> 1, wn = w & 1;
  const int fr = lane & 15, quad = lane >> 4;
  const int m0 = blockIdx.y * 128, n0 = blockIdx.x * 128;
  const int srow = w * 32 + (lane >> 2);
  const int scol = (lane & 3) * 8;
  const f16* pA = A + (size_t)(m0 + srow) * K + scol;
  const f16* pW = W + (size_t)(n0 + srow) * K + scol;
  const size_t rstep = (size_t)16 * K;
  const int lo = w * 1024;

  f32x4 acc[4][4] = {};

#define STAGE_G(b, k)                           \
  gload16(pA + (k), &sA[b][lo]);                \
  gload16(pA + rstep + (k), &sA[b][lo + 512]);  \
  gload16(pW + (k), &sW[b][lo]);                \
  gload16(pW + rstep + (k), &sW[b][lo + 512]);

#define COMPUTE_G(b)                                       \
  {                                                        \
    f16x8 af[4], bf[4];                                    \
    _Pragma("unroll") for (int i = 0; i < 4; ++i) {        \
      int r = (wm * 64 + i * 16 + fr) * 32 + quad * 8;     \
      af[i] = *(const f16x8*)&sA[b][r];                    \
    }                                                      \
    _Pragma("unroll") for (int j = 0; j < 4; ++j) {        \
      int r = (wn * 64 + j * 16 + fr) * 32 + quad * 8;     \
      bf[j] = *(const f16x8*)&sW[b][r];                    \
    }                                                      \
    _Pragma("unroll") for (int i = 0; i < 4; ++i)          \
      _Pragma("unroll") for (int j = 0; j < 4; ++j)        \
          acc[i][j] = MFMA16(af[i], bf[j], acc[i][j]);     \
  }

  // prologue: fill buffer 0, drain, go
  STAGE_G(0, 0);
  __syncthreads();
  for (int k0 = 0; k0 < K; k0 += 64) {
    STAGE_G(1, k0 + 32);      // prefetch in flight during compute(0)
    COMPUTE_G(0);
    __syncthreads();          // drains prefetch vmcnt + syncs waves
    if (k0 + 64 < K) { STAGE_G(0, k0 + 64); }
    COMPUTE_G(1);
    __syncthreads();
  }
#undef STAGE_G
#undef COMPUTE_G

  // C/D map: col = lane&15, row = quad*4 + reg
  bool is_h1 = true;
  const float* bp = bias;
  int nb0 = n0;
  if (EPI == 1) {
    is_h1 = (n0 < 2048);
    bp = is_h1 ? bias : bias2;
    nb0 = is_h1 ? n0 : n0 - 2048;
  }
#pragma unroll
  for (int j = 0; j < 4; ++j) {
    int n = nb0 + wn * 64 + j * 16 + fr;
    float bv = bp[n];
#pragma unroll
    for (int i = 0; i < 4; ++i) {
      int mb = m0 + wm * 64 + i * 16 + quad * 4;
      if (EPI == 0) {
        // packed store: one f16x4 covering rows mb..mb+3 at column n
        f16x4 o = {(f16)(acc[i][j][0] + bv), (f16)(acc[i][j][1] + bv),
                   (f16)(acc[i][j][2] + bv), (f16)(acc[i][j][3] + bv)};
        *(f16x4*)&Ch[((size_t)(mb >> 2) * N + n) * 4] = o;
      } else {
#pragma unroll
        for (int r = 0; r < 4; ++r) {
          int m = mb + r;
          float v = acc[i][j][r] + bv;
          if (EPI == 1) {
            float vr = fmaxf(v, 0.0f);
            if (is_h1)
              Ch[(size_t)m * HDIM + n] = (f16)vr;
            else
              Cf[(size_t)m * LDIM + n] = vr;
          } else {
            Cout[(size_t)m * N + n] = v;
            f16 t = (f16)fast_tanh(v);
            size_t c = (size_t)m * JDIM + 1024 + n;
            aXH[c] = t;
            aJH[c] = t;
          }
        }
      }
    }
  }
}

// ============================================================================
// Fused GRU cycle: h_gates = state @ W_hh^T + b_hh (r,z,n) + gate update.
// Block: 128(M) x 64(N per gate) x 3 gates. 4 waves, wave = 32(M)x64(N).
// Double-buffered prefetch K-loop (same scheme as gemm_f16).
// xg is PACKED [m/4][3072][4]: epilogue loads one f16x4 per gate per frag
// (24 vec loads/thread instead of 96 scalar), 128B-coalesced across lanes.
// ============================================================================
__global__ __launch_bounds__(256, 2) void gru_fused(
    const f16* __restrict__ inH, const f16* __restrict__ Whh,
    const float* __restrict__ bhh, const f16* __restrict__ xgP,
    f16* __restrict__ outH, f16* __restrict__ catJH) {
  __shared__ f16 sA[2][128 * 32];
  __shared__ f16 sW0[2][64 * 32];
  __shared__ f16 sW1[2][64 * 32];
  __shared__ f16 sW2[2][64 * 32];
  const int tid = threadIdx.x;
  const int w = tid >> 6, lane = tid & 63;
  const int fr = lane & 15, quad = lane >> 4;
  const int n0 = blockIdx.x * 64, m0 = blockIdx.y * 128;
  const int srow = w * 32 + (lane >> 2);
  const int scol = (lane & 3) * 8;
  const f16* pA = inH + (size_t)(m0 + srow) * LDIM + scol;
  const size_t rstepA = (size_t)16 * LDIM;
  const int wrow = w * 16 + (lane >> 2);
  const f16* pW0 = Whh + (size_t)(n0 + wrow) * LDIM + scol;
  const f16* pW1 = pW0 + (size_t)LDIM * LDIM;
  const f16* pW2 = pW1 + (size_t)LDIM * LDIM;
  const int loA = w * 1024, loW = w * 512;

  f32x4 ar[2][4] = {}, az[2][4] = {}, an_[2][4] = {};

#define STAGE_R(b, k)                             \
  gload16(pA + (k), &sA[b][loA]);                 \
  gload16(pA + rstepA + (k), &sA[b][loA + 512]);  \
  gload16(pW0 + (k), &sW0[b][loW]);               \
  gload16(pW1 + (k), &sW1[b][loW]);               \
  gload16(pW2 + (k), &sW2[b][loW]);

#define COMPUTE_R(b)                                   \
  {                                                    \
    f16x8 a_[2], w0[4], w1[4], w2[4];                  \
    _Pragma("unroll") for (int i = 0; i < 2; ++i) {    \
      int r = (w * 32 + i * 16 + fr) * 32 + quad * 8;  \
      a_[i] = *(const f16x8*)&sA[b][r];                \
    }                                                  \
    _Pragma("unroll") for (int j = 0; j < 4; ++j) {    \
      int r = (j * 16 + fr) * 32 + quad * 8;           \
      w0[j] = *(const f16x8*)&sW0[b][r];               \
      w1[j] = *(const f16x8*)&sW1[b][r];               \
      w2[j] = *(const f16x8*)&sW2[b][r];               \
    }                                                  \
    _Pragma("unroll") for (int i = 0; i < 2; ++i)      \
      _Pragma("unroll") for (int j = 0; j < 4; ++j) {  \
        ar[i][j] = MFMA16(a_[i], w0[j], ar[i][j]);     \
        az[i][j] = MFMA16(a_[i], w1[j], az[i][j]);     \
        an_[i][j] = MFMA16(a_[i], w2[j], an_[i][j]);   \
      }                                                \
  }

  STAGE_R(0, 0);
  __syncthreads();
  for (int k0 = 0; k0 < LDIM; k0 += 64) {
    STAGE_R(1, k0 + 32);
    COMPUTE_R(0);
    __syncthreads();
    if (k0 + 64 < LDIM) { STAGE_R(0, k0 + 64); }
    COMPUTE_R(1);
    __syncthreads();
  }
#undef STAGE_R
#undef COMPUTE_R

  // epilogue: full GRU gate update; xg loads are f16x4 (packed layout)
#pragma unroll
  for (int j = 0; j < 4; ++j) {
    int col = n0 + j * 16 + fr;
    float br = bhh[col], bz = bhh[col + LDIM], bn = bhh[col + 2 * LDIM];
#pragma unroll
    for (int i = 0; i < 2; ++i) {
      int mb = m0 + w * 32 + i * 16 + quad * 4;
      size_t xb = ((size_t)(mb >> 2) * GDIM + col) * 4;
      f16x4 x4r = *(const f16x4*)&xgP[xb];
      f16x4 x4z = *(const f16x4*)&xgP[xb + (size_t)LDIM * 4];
      f16x4 x4n = *(const f16x4*)&xgP[xb + (size_t)2 * LDIM * 4];
#pragma unroll
      for (int r = 0; r < 4; ++r) {
        int m = mb + r;
        size_t si = (size_t)m * LDIM + col;
        float sold = (float)inH[si];
        float rg = fast_sigmoid((float)x4r[r] + ar[i][j][r] + br);
        float zg = fast_sigmoid((float)x4z[r] + az[i][j][r] + bz);
        float ng = fast_tanh((float)x4n[r] + rg * (an_[i][j][r] + bn));
        float o = (1.0f - zg) * ng + zg * sold;
        f16 oh = (f16)o;
        outH[si] = oh;
        if (catJH) catJH[(size_t)m * JDIM + col] = oh;
      }
    }
  }
}

// halt = h2[B,1024] @ hw2[2,1024]^T + hb2; one wave per row.
__global__ __launch_bounds__(256) void halt_kernel(
    const float* __restrict__ h2, const float* __restrict__ hw2,
    const float* __restrict__ hb2, float* __restrict__ out) {
  int wave = (blockIdx.x * 256 + threadIdx.x) >> 6;
  int lane = threadIdx.x & 63;
  if (wave >= BATCH) return;
  const float* row = h2 + (size_t)wave * LDIM;
  float s0 = 0.0f, s1 = 0.0f;
#pragma unroll
  for (int k = lane; k < LDIM; k += 64) {
    float v = row[k];
    s0 = fmaf(v, hw2[k], s0);
    s1 = fmaf(v, hw2[LDIM + k], s1);
  }
#pragma unroll
  for (int off = 32; off > 0; off >>= 1) {
    s0 += __shfl_xor(s0, off);
    s1 += __shfl_xor(s1, off);
  }
  if (lane == 0) {
    out[(size_t)wave * 2 + 0] = s0 + hb2[0];
    out[(size_t)wave * 2 + 1] = s1 + hb2[1];
  }
}

extern "C" void kernel_launch(void* const* d_in, const int* in_sizes, int n_in,
                              void* d_out, int out_size, void* d_ws, size_t ws_size,
                              hipStream_t stream) {
  const float* inputs = (const float*)d_in[0];
  const float* W_ih = (const float*)d_in[1];
  const float* W_hh = (const float*)d_in[2];
  const float* b_ih = (const float*)d_in[3];
  const float* b_hh = (const float*)d_in[4];
  const float* aw1 = (const float*)d_in[5];
  const float* ab1 = (const float*)d_in[6];
  const float* aw2 = (const float*)d_in[7];
  const float* ab2 = (const float*)d_in[8];
  const float* hw1 = (const float*)d_in[9];
  const float* hb1 = (const float*)d_in[10];
  const float* hw2 = (const float*)d_in[11];
  const float* hb2 = (const float*)d_in[12];

  float* out = (float*)d_out;
  float* logits_out = out;                               // [8, B, 512]
  float* halt_out = out + (size_t)OUTER * BATCH * ODIM;  // [8, B, 2]

  char* p = (char*)d_ws;
  auto take = [&](size_t bytes) { char* q = p; p += (bytes + 255) & ~255ull; return q; };
  f16* stA = (f16*)take((size_t)BATCH * LDIM * 2);
  f16* stB = (f16*)take((size_t)BATCH * LDIM * 2);
  f16* catX = (f16*)take((size_t)BATCH * JDIM * 2);
  f16* catJ = (f16*)take((size_t)BATCH * JDIM * 2);
  f16* xg = (f16*)take((size_t)BATCH * GDIM * 2);       // 25 MB, PACKED layout
  float* h2F = (float*)take((size_t)BATCH * LDIM * 4);
  f16* WihF = (f16*)take((size_t)GDIM * JDIM * 2);
  f16* WhhF = (f16*)take((size_t)GDIM * LDIM * 2);
  f16* WjF = (f16*)take((size_t)(HDIM + LDIM) * JDIM * 2);  // [aw1; hw1]
  f16* aw2F = (f16*)take((size_t)ODIM * HDIM * 2);
  // overlay: h1 fp16 [B,2048] lives in xg region (xg dead after GRU cycles,
  // h1 dead before next step's xg GEMM)
  f16* h1 = xg;

  (void)hipMemsetAsync(stA, 0, (size_t)BATCH * LDIM * 2, stream);
  (void)hipMemsetAsync(catX, 0, (size_t)BATCH * JDIM * 2, stream);
  (void)hipMemsetAsync(catJ, 0, (size_t)BATCH * JDIM * 2, stream);

  auto conv = [&](const float* s, f16* d, size_t n) {
    int n4 = (int)(n / 4);
    convert_w<<<(n4 + 255) / 256, 256, 0, stream>>>(s, d, n4);
  };
  conv(W_ih, WihF, (size_t)GDIM * JDIM);
  conv(W_hh, WhhF, (size_t)GDIM * LDIM);
  conv(aw1, WjF, (size_t)HDIM * JDIM);
  conv(hw1, WjF + (size_t)HDIM * JDIM, (size_t)LDIM * JDIM);
  conv(aw2, aw2F, (size_t)ODIM * HDIM);
  input_to_cat<<<BATCH, 256, 0, stream>>>(inputs, catX);

  for (int s = 0; s < OUTER; ++s) {
    // x_gates = [inputs|ans] @ W_ih^T + b_ih -> PACKED fp16 xg
    gemm_f16<0><<<dim3(GDIM / 128, BATCH / 128), 256, 0, stream>>>(
        catX, WihF, b_ih, nullptr, xg, nullptr, nullptr, nullptr, nullptr,
        GDIM, JDIM);
    // 4 fused GRU cycles, ping-pong; last writes catJ state cols
    f16 *cur = stA, *nxt = stB;
    for (int c = 0; c < INNER; ++c) {
      bool last = (c == INNER - 1);
      gru_fused<<<dim3(LDIM / 64, BATCH / 128), 256, 0, stream>>>(
          cur, WhhF, b_hh, xg, nxt, last ? catJ : nullptr);
      f16* t = cur; cur = nxt; nxt = t;
    }
    // h1 = relu(joint @ aw1^T + ab1) fp16 (overlay xg);
    // h2 = relu(joint @ hw1^T + hb1) fp32 — one combined N=3072 GEMM
    gemm_f16<1><<<dim3((HDIM + LDIM) / 128, BATCH / 128), 256, 0, stream>>>(
        catJ, WjF, ab1, hb1, h1, h2F, nullptr, nullptr, nullptr,
        HDIM + LDIM, JDIM);
    // logits = h1 @ aw2^T + ab2 -> out; ans = tanh -> catX/catJ ans cols
    gemm_f16<2><<<dim3(ODIM / 128, BATCH / 128), 256, 0, stream>>>(
        h1, aw2F, ab2, nullptr, nullptr, nullptr,
        logits_out + (size_t)s * BATCH * ODIM, catX, catJ, ODIM, HDIM);
    // halt = h2 @ hw2^T + hb2 -> out
    halt_kernel<<<BATCH / 4, 256, 0, stream>>>(
        h2F, hw2, hb2, halt_out + (size_t)s * BATCH * 2);
  }
}

// Round 2
// 2726.497 us; speedup vs baseline: 1.1792x; 1.0468x over previous
//
#include <hip/hip_runtime.h>
#include <math.h>

#define BATCH 4096
#define LDIM 1024
#define HDIM 2048
#define ODIM 512
#define GDIM 3072   // 3*LDIM
#define JDIM 1536   // IDIM+ODIM == LDIM+ODIM
#define INNER 4
#define OUTER 8

using f16 = _Float16;
using f16x4 = __attribute__((ext_vector_type(4))) _Float16;
using f16x8 = __attribute__((ext_vector_type(8))) _Float16;
using f32x4 = __attribute__((ext_vector_type(4))) float;

typedef __attribute__((address_space(3))) void lds_void;
typedef __attribute__((address_space(1))) void glob_void;

__device__ __forceinline__ void gload16(const void* g, void* l) {
  __builtin_amdgcn_global_load_lds((const glob_void*)g, (lds_void*)l, 16, 0, 0);
}

#define MFMA16(a, b, c) __builtin_amdgcn_mfma_f32_16x16x32_f16(a, b, c, 0, 0, 0)
// counted vmcnt wait: keeps prefetch loads in flight across raw s_barrier
#define WAIT_VM(N) asm volatile("s_waitcnt vmcnt(" #N ")" ::: "memory")

__device__ __forceinline__ float fast_sigmoid(float x) {
  return __builtin_amdgcn_rcpf(1.0f + __expf(-x));
}
__device__ __forceinline__ float fast_tanh(float x) {
  return 1.0f - 2.0f * __builtin_amdgcn_rcpf(1.0f + __expf(2.0f * x));
}

// fp32 -> fp16 (RTN), n4 = elems/4
__global__ __launch_bounds__(256) void convert_w(const float* __restrict__ src,
                                                 f16* __restrict__ dst, int n4) {
  int i = blockIdx.x * 256 + threadIdx.x;
  if (i >= n4) return;
  float4 v = ((const float4*)src)[i];
  f16x4 d = {(f16)v.x, (f16)v.y, (f16)v.z, (f16)v.w};
  *(f16x4*)&dst[(size_t)i * 4] = d;
}

// inputs [B,1024] fp32 -> cols [0,1024) of catX [B,1536] fp16
__global__ __launch_bounds__(256) void input_to_cat(
    const float* __restrict__ inp, f16* __restrict__ cH) {
  int idx = blockIdx.x * 256 + threadIdx.x;  // over B*256 float4s
  if (idx >= BATCH * 256) return;
  int row = idx >> 8, c4 = idx & 255;
  float4 v = ((const float4*)inp)[idx];
  f16x4 h4 = {(f16)v.x, (f16)v.y, (f16)v.z, (f16)v.w};
  *(f16x4*)&cH[(size_t)row * JDIM + c4 * 4] = h4;
}

// ============================================================================
// fp16 GEMM: C[4096, N] = epi(A @ W^T + bias). A fp16 [M][K], W fp16 [N][K].
// Tile 128x128, BK=32, 4 waves (2x2), wave 64x64 = 4x4 frags.
// TRIPLE-buffered LDS + counted vmcnt: stage tile t+2 while computing tile t;
// one raw s_barrier per K-step, s_waitcnt vmcnt(4) (never 0 in steady state).
// T2 swizzle: LDS dest linear (global_load_lds requirement), SOURCE column
// pre-swizzled chunk = (lane&3)^((lane>>3)&3); read applies same XOR
// slot = quad ^ ((row>>1)&3) -> 2-way max bank aliasing (free).
// EPI: 0 = PACKED fp16 C ([m/4][N][4], f16x4 along m = MFMA C-frag rows)
//      1 = joint head: relu; n<2048 -> h1 fp16 (bias), n>=2048 -> h2 fp32 (bias2)
//      2 = logits: fp32 Cout (N=512) + tanh -> fp16 into catX/catJ ans cols
// ============================================================================
template <int EPI>
__global__ __launch_bounds__(256, 2) void gemm_f16(
    const f16* __restrict__ A, const f16* __restrict__ W,
    const float* __restrict__ bias, const float* __restrict__ bias2,
    f16* __restrict__ Ch, float* __restrict__ Cf, float* __restrict__ Cout,
    f16* __restrict__ aXH, f16* __restrict__ aJH, int N, int K) {
  __shared__ f16 sA[3][128 * 32];
  __shared__ f16 sW[3][128 * 32];
  const int tid = threadIdx.x;
  const int w = tid >> 6, lane = tid & 63;
  const int wm = w >> 1, wn = w & 1;
  const int fr = lane & 15, quad = lane >> 4;
  const int m0 = blockIdx.y * 128, n0 = blockIdx.x * 128;
  const int srow = w * 32 + (lane >> 2);
  const int scol = (((lane & 3) ^ ((lane >> 3) & 3)) * 8);  // swizzled source
  const f16* pA = A + (size_t)(m0 + srow) * K + scol;
  const f16* pW = W + (size_t)(n0 + srow) * K + scol;
  const size_t rstep = (size_t)16 * K;
  const int lo = w * 1024;

  f32x4 acc[4][4] = {};
  const int NT = K >> 5;

  auto stage = [&](int b, int k) {
    gload16(pA + k, &sA[b][lo]);
    gload16(pA + rstep + k, &sA[b][lo + 512]);
    gload16(pW + k, &sW[b][lo]);
    gload16(pW + rstep + k, &sW[b][lo + 512]);
  };
  stage(0, 0);
  stage(1, 32);
  int bb = 0;
  for (int t = 0; t < NT; ++t) {
    if (t == NT - 1) { WAIT_VM(0); } else { WAIT_VM(4); }
    __builtin_amdgcn_s_barrier();
    if (t + 2 < NT) {
      int bn = bb + 2; if (bn >= 3) bn -= 3;
      stage(bn, (t + 2) * 32);
    }
    f16x8 af[4], bf[4];
#pragma unroll
    for (int i = 0; i < 4; ++i) {
      int rr = wm * 64 + i * 16 + fr;
      af[i] = *(const f16x8*)&sA[bb][rr * 32 + ((quad ^ ((rr >> 1) & 3)) << 3)];
    }
#pragma unroll
    for (int j = 0; j < 4; ++j) {
      int rr = wn * 64 + j * 16 + fr;
      bf[j] = *(const f16x8*)&sW[bb][rr * 32 + ((quad ^ ((rr >> 1) & 3)) << 3)];
    }
    __builtin_amdgcn_s_setprio(1);
#pragma unroll
    for (int i = 0; i < 4; ++i)
#pragma unroll
      for (int j = 0; j < 4; ++j) acc[i][j] = MFMA16(af[i], bf[j], acc[i][j]);
    __builtin_amdgcn_s_setprio(0);
    if (++bb == 3) bb = 0;
  }

  // C/D map: col = lane&15, row = quad*4 + reg
  bool is_h1 = true;
  const float* bp = bias;
  int nb0 = n0;
  if (EPI == 1) {
    is_h1 = (n0 < 2048);
    bp = is_h1 ? bias : bias2;
    nb0 = is_h1 ? n0 : n0 - 2048;
  }
#pragma unroll
  for (int j = 0; j < 4; ++j) {
    int n = nb0 + wn * 64 + j * 16 + fr;
    float bv = bp[n];
#pragma unroll
    for (int i = 0; i < 4; ++i) {
      int mb = m0 + wm * 64 + i * 16 + quad * 4;
      if (EPI == 0) {
        f16x4 o = {(f16)(acc[i][j][0] + bv), (f16)(acc[i][j][1] + bv),
                   (f16)(acc[i][j][2] + bv), (f16)(acc[i][j][3] + bv)};
        *(f16x4*)&Ch[((size_t)(mb >> 2) * N + n) * 4] = o;
      } else {
#pragma unroll
        for (int r = 0; r < 4; ++r) {
          int m = mb + r;
          float v = acc[i][j][r] + bv;
          if (EPI == 1) {
            float vr = fmaxf(v, 0.0f);
            if (is_h1)
              Ch[(size_t)m * HDIM + n] = (f16)vr;
            else
              Cf[(size_t)m * LDIM + n] = vr;
          } else {
            Cout[(size_t)m * N + n] = v;
            f16 t = (f16)fast_tanh(v);
            size_t c = (size_t)m * JDIM + 1024 + n;
            aXH[c] = t;
            aJH[c] = t;
          }
        }
      }
    }
  }
}

// ============================================================================
// Fused GRU cycle: h_gates = state @ W_hh^T + b_hh (r,z,n) + gate update.
// Block: 128(M) x 64(N per gate) x 3 gates. 4 waves, wave = 32(M)x64(N).
// Same triple-buffer + counted vmcnt(5) + swizzle scheme as gemm_f16.
// xg PACKED [m/4][3072][4]: f16x4 loads, coalesced.
// ============================================================================
__global__ __launch_bounds__(256, 2) void gru_fused(
    const f16* __restrict__ inH, const f16* __restrict__ Whh,
    const float* __restrict__ bhh, const f16* __restrict__ xgP,
    f16* __restrict__ outH, f16* __restrict__ catJH) {
  __shared__ f16 sA[3][128 * 32];
  __shared__ f16 sW0[3][64 * 32];
  __shared__ f16 sW1[3][64 * 32];
  __shared__ f16 sW2[3][64 * 32];
  const int tid = threadIdx.x;
  const int w = tid >> 6, lane = tid & 63;
  const int fr = lane & 15, quad = lane >> 4;
  const int n0 = blockIdx.x * 64, m0 = blockIdx.y * 128;
  const int srow = w * 32 + (lane >> 2);
  const int scol = (((lane & 3) ^ ((lane >> 3) & 3)) * 8);  // swizzled source
  const f16* pA = inH + (size_t)(m0 + srow) * LDIM + scol;
  const size_t rstepA = (size_t)16 * LDIM;
  const int wrow = w * 16 + (lane >> 2);
  const f16* pW0 = Whh + (size_t)(n0 + wrow) * LDIM + scol;
  const f16* pW1 = pW0 + (size_t)LDIM * LDIM;
  const f16* pW2 = pW1 + (size_t)LDIM * LDIM;
  const int loA = w * 1024, loW = w * 512;

  f32x4 ar[2][4] = {}, az[2][4] = {}, an_[2][4] = {};
  const int NT = LDIM >> 5;  // 32

  auto stage = [&](int b, int k) {
    gload16(pA + k, &sA[b][loA]);
    gload16(pA + rstepA + k, &sA[b][loA + 512]);
    gload16(pW0 + k, &sW0[b][loW]);
    gload16(pW1 + k, &sW1[b][loW]);
    gload16(pW2 + k, &sW2[b][loW]);
  };
  stage(0, 0);
  stage(1, 32);
  int bb = 0;
  for (int t = 0; t < NT; ++t) {
    if (t == NT - 1) { WAIT_VM(0); } else { WAIT_VM(5); }
    __builtin_amdgcn_s_barrier();
    if (t + 2 < NT) {
      int bn = bb + 2; if (bn >= 3) bn -= 3;
      stage(bn, (t + 2) * 32);
    }
    f16x8 a_[2], w0[4], w1[4], w2[4];
#pragma unroll
    for (int i = 0; i < 2; ++i) {
      int rr = w * 32 + i * 16 + fr;
      a_[i] = *(const f16x8*)&sA[bb][rr * 32 + ((quad ^ ((rr >> 1) & 3)) << 3)];
    }
#pragma unroll
    for (int j = 0; j < 4; ++j) {
      int rw = j * 16 + fr;
      int wo = rw * 32 + ((quad ^ ((rw >> 1) & 3)) << 3);
      w0[j] = *(const f16x8*)&sW0[bb][wo];
      w1[j] = *(const f16x8*)&sW1[bb][wo];
      w2[j] = *(const f16x8*)&sW2[bb][wo];
    }
    __builtin_amdgcn_s_setprio(1);
#pragma unroll
    for (int i = 0; i < 2; ++i)
#pragma unroll
      for (int j = 0; j < 4; ++j) {
        ar[i][j] = MFMA16(a_[i], w0[j], ar[i][j]);
        az[i][j] = MFMA16(a_[i], w1[j], az[i][j]);
        an_[i][j] = MFMA16(a_[i], w2[j], an_[i][j]);
      }
    __builtin_amdgcn_s_setprio(0);
    if (++bb == 3) bb = 0;
  }

  // epilogue: full GRU gate update; xg loads are f16x4 (packed layout)
#pragma unroll
  for (int j = 0; j < 4; ++j) {
    int col = n0 + j * 16 + fr;
    float br = bhh[col], bz = bhh[col + LDIM], bn = bhh[col + 2 * LDIM];
#pragma unroll
    for (int i = 0; i < 2; ++i) {
      int mb = m0 + w * 32 + i * 16 + quad * 4;
      size_t xb = ((size_t)(mb >> 2) * GDIM + col) * 4;
      f16x4 x4r = *(const f16x4*)&xgP[xb];
      f16x4 x4z = *(const f16x4*)&xgP[xb + (size_t)LDIM * 4];
      f16x4 x4n = *(const f16x4*)&xgP[xb + (size_t)2 * LDIM * 4];
#pragma unroll
      for (int r = 0; r < 4; ++r) {
        int m = mb + r;
        size_t si = (size_t)m * LDIM + col;
        float sold = (float)inH[si];
        float rg = fast_sigmoid((float)x4r[r] + ar[i][j][r] + br);
        float zg = fast_sigmoid((float)x4z[r] + az[i][j][r] + bz);
        float ng = fast_tanh((float)x4n[r] + rg * (an_[i][j][r] + bn));
        float o = (1.0f - zg) * ng + zg * sold;
        f16 oh = (f16)o;
        outH[si] = oh;
        if (catJH) catJH[(size_t)m * JDIM + col] = oh;
      }
    }
  }
}

// halt = h2[B,1024] @ hw2[2,1024]^T + hb2; one wave per row.
__global__ __launch_bounds__(256) void halt_kernel(
    const float* __restrict__ h2, const float* __restrict__ hw2,
    const float* __restrict__ hb2, float* __restrict__ out) {
  int wave = (blockIdx.x * 256 + threadIdx.x) >> 6;
  int lane = threadIdx.x & 63;
  if (wave >= BATCH) return;
  const float* row = h2 + (size_t)wave * LDIM;
  float s0 = 0.0f, s1 = 0.0f;
#pragma unroll
  for (int k = lane; k < LDIM; k += 64) {
    float v = row[k];
    s0 = fmaf(v, hw2[k], s0);
    s1 = fmaf(v, hw2[LDIM + k], s1);
  }
#pragma unroll
  for (int off = 32; off > 0; off >>= 1) {
    s0 += __shfl_xor(s0, off);
    s1 += __shfl_xor(s1, off);
  }
  if (lane == 0) {
    out[(size_t)wave * 2 + 0] = s0 + hb2[0];
    out[(size_t)wave * 2 + 1] = s1 + hb2[1];
  }
}

extern "C" void kernel_launch(void* const* d_in, const int* in_sizes, int n_in,
                              void* d_out, int out_size, void* d_ws, size_t ws_size,
                              hipStream_t stream) {
  const float* inputs = (const float*)d_in[0];
  const float* W_ih = (const float*)d_in[1];
  const float* W_hh = (const float*)d_in[2];
  const float* b_ih = (const float*)d_in[3];
  const float* b_hh = (const float*)d_in[4];
  const float* aw1 = (const float*)d_in[5];
  const float* ab1 = (const float*)d_in[6];
  const float* aw2 = (const float*)d_in[7];
  const float* ab2 = (const float*)d_in[8];
  const float* hw1 = (const float*)d_in[9];
  const float* hb1 = (const float*)d_in[10];
  const float* hw2 = (const float*)d_in[11];
  const float* hb2 = (const float*)d_in[12];

  float* out = (float*)d_out;
  float* logits_out = out;                               // [8, B, 512]
  float* halt_out = out + (size_t)OUTER * BATCH * ODIM;  // [8, B, 2]

  char* p = (char*)d_ws;
  auto take = [&](size_t bytes) { char* q = p; p += (bytes + 255) & ~255ull; return q; };
  f16* stA = (f16*)take((size_t)BATCH * LDIM * 2);
  f16* stB = (f16*)take((size_t)BATCH * LDIM * 2);
  f16* catX = (f16*)take((size_t)BATCH * JDIM * 2);
  f16* catJ = (f16*)take((size_t)BATCH * JDIM * 2);
  f16* xg = (f16*)take((size_t)BATCH * GDIM * 2);       // 25 MB, PACKED layout
  float* h2F = (float*)take((size_t)BATCH * LDIM * 4);
  f16* WihF = (f16*)take((size_t)GDIM * JDIM * 2);
  f16* WhhF = (f16*)take((size_t)GDIM * LDIM * 2);
  f16* WjF = (f16*)take((size_t)(HDIM + LDIM) * JDIM * 2);  // [aw1; hw1]
  f16* aw2F = (f16*)take((size_t)ODIM * HDIM * 2);
  // overlay: h1 fp16 [B,2048] lives in xg region (xg dead after GRU cycles,
  // h1 dead before next step's xg GEMM)
  f16* h1 = xg;

  (void)hipMemsetAsync(stA, 0, (size_t)BATCH * LDIM * 2, stream);
  (void)hipMemsetAsync(catX, 0, (size_t)BATCH * JDIM * 2, stream);
  (void)hipMemsetAsync(catJ, 0, (size_t)BATCH * JDIM * 2, stream);

  auto conv = [&](const float* s, f16* d, size_t n) {
    int n4 = (int)(n / 4);
    convert_w<<<(n4 + 255) / 256, 256, 0, stream>>>(s, d, n4);
  };
  conv(W_ih, WihF, (size_t)GDIM * JDIM);
  conv(W_hh, WhhF, (size_t)GDIM * LDIM);
  conv(aw1, WjF, (size_t)HDIM * JDIM);
  conv(hw1, WjF + (size_t)HDIM * JDIM, (size_t)LDIM * JDIM);
  conv(aw2, aw2F, (size_t)ODIM * HDIM);
  input_to_cat<<<BATCH, 256, 0, stream>>>(inputs, catX);

  for (int s = 0; s < OUTER; ++s) {
    // x_gates = [inputs|ans] @ W_ih^T + b_ih -> PACKED fp16 xg
    gemm_f16<0><<<dim3(GDIM / 128, BATCH / 128), 256, 0, stream>>>(
        catX, WihF, b_ih, nullptr, xg, nullptr, nullptr, nullptr, nullptr,
        GDIM, JDIM);
    // 4 fused GRU cycles, ping-pong; last writes catJ state cols
    f16 *cur = stA, *nxt = stB;
    for (int c = 0; c < INNER; ++c) {
      bool last = (c == INNER - 1);
      gru_fused<<<dim3(LDIM / 64, BATCH / 128), 256, 0, stream>>>(
          cur, WhhF, b_hh, xg, nxt, last ? catJ : nullptr);
      f16* t = cur; cur = nxt; nxt = t;
    }
    // h1 = relu(joint @ aw1^T + ab1) fp16 (overlay xg);
    // h2 = relu(joint @ hw1^T + hb1) fp32 — one combined N=3072 GEMM
    gemm_f16<1><<<dim3((HDIM + LDIM) / 128, BATCH / 128), 256, 0, stream>>>(
        catJ, WjF, ab1, hb1, h1, h2F, nullptr, nullptr, nullptr,
        HDIM + LDIM, JDIM);
    // logits = h1 @ aw2^T + ab2 -> out; ans = tanh -> catX/catJ ans cols
    gemm_f16<2><<<dim3(ODIM / 128, BATCH / 128), 256, 0, stream>>>(
        h1, aw2F, ab2, nullptr, nullptr, nullptr,
        logits_out + (size_t)s * BATCH * ODIM, catX, catJ, ODIM, HDIM);
    // halt = h2 @ hw2^T + hb2 -> out
    halt_kernel<<<BATCH / 4, 256, 0, stream>>>(
        h2F, hw2, hb2, halt_out + (size_t)s * BATCH * 2);
  }
}